// Round 5
// baseline (117.316 us; speedup 1.0000x reference)
//
#include <hip/hip_runtime.h>
#include <hip/hip_fp16.h>

#define OUT_H 512
#define OUT_W 512
#define BATCH 64
#define CHANS 3

#define LROWS 47
#define LPITCH 49   // px per row; 49*8B=392B = 98 dwords ≡ 2 mod 32 banks (no row-aliasing)

__global__ __launch_bounds__(256) void st_bilinear_kernel(
    const float* __restrict__ U,      // [B, H, W, C] f32
    const float* __restrict__ theta,  // [B, 1]
    float* __restrict__ out)          // [B, H, W, C] f32
{
    // +1 slot: corner read idx+LPITCH+1 of a masked pixel can touch 2303.
    __shared__ uint2 sm[LROWS * LPITCH + 1];   // 18432 B -> 8 blocks/CU

    // XCD-aware remap: give XCD k images [k*8, k*8+8) so each 3.1 MB image
    // stays resident in one XCD's 4 MB L2.
    int blk  = blockIdx.x;
    int lblk = (blk & 7) * 2048 + (blk >> 3);

    int b  = lblk >> 8;                 // image (uniform per block)
    int t  = lblk & 255;                // 16x16 tiles of 32x32 px
    int i0 = (t >> 4) << 5;
    int j0 = (t & 15) << 5;

    int tid = threadIdx.x;

    float tt = theta[b];
    float s, c;
    __sincosf(tt, &s, &c);

    // x = xb0 + c*jl - s*il ; y = yb0 + s*jl + c*il  ((2/511)*255.5 == 1)
    const float scale = 2.0f / 511.0f;
    float gx0 = (float)j0 * scale - 1.0f;
    float gy0 = (float)i0 * scale - 1.0f;
    float xb0 = (c * gx0 - s * gy0 + 1.0f) * 255.5f;
    float yb0 = (s * gx0 + c * gy0 + 1.0f) * 255.5f;

    // Source bbox of the 32x32 tile (linear map -> corner extremes).
    float xmin = xb0 + fminf(0.0f, 31.0f * c) + fminf(0.0f, -31.0f * s);
    float ymin = yb0 + fminf(0.0f, 31.0f * s) + fminf(0.0f,  31.0f * c);

    int bx0 = min(max((int)floorf(xmin), 0), OUT_W - 1);
    int by0 = min(max((int)floorf(ymin), 0), OUT_H - 1);
    int bx_load = min(bx0, OUT_W - 48);   // window always fully in-image
    int by_load = min(by0, OUT_H - 46);

    // Stage 46 rows x 48 px as packed f16 {c0,c1 | c2,pad} (8 B/px).
    const float* Ub = U + (size_t)b * (OUT_H * OUT_W * CHANS);
    const float* gb = Ub + ((size_t)by_load * OUT_W + bx_load) * CHANS;
    for (int u = tid; u < 46 * 48; u += 256) {
        int r  = u / 48;                 // compiler magic-mul
        int px = u - r * 48;
        const float* p = gb + (size_t)r * (OUT_W * CHANS) + px * CHANS;
        float2 c01 = *(const float2*)p;
        float  c2  = p[2];
        __half2 h01 = __floats2half2_rn(c01.x, c01.y);
        __half2 h2  = __floats2half2_rn(c2, 0.0f);
        uint2 v;
        v.x = *(const unsigned int*)&h01;
        v.y = *(const unsigned int*)&h2;
        sm[r * LPITCH + px] = v;
    }
    __syncthreads();

    // One pass: thread -> 4 consecutive output px in one row.
    int il = tid >> 3;                  // 0..31
    int jb = (tid & 7) << 2;            // 0,4,...,28
    float ilf = (float)il;
    float xr = xb0 - s * ilf;           // x at (il, j0+0)
    float yr = yb0 + c * ilf;

    float o[12];
#pragma unroll
    for (int p = 0; p < 4; ++p) {
        float jlf = (float)(jb + p);
        float x = fmaf(c, jlf, xr);
        float y = fmaf(s, jlf, yr);

        float x0f = floorf(x);
        float y0f = floorf(y);
        float fx = x - x0f;
        float fy = y - y0f;
        float hx = 1.0f - fx;
        float hy = 1.0f - fy;
        __half2 wa2 = __float2half2_rn(hx * hy);   // (y0,x0)
        __half2 wb2 = __float2half2_rn(hx * fy);   // (y1,x0)
        __half2 wc2 = __float2half2_rn(fx * hy);   // (y0,x1)
        __half2 wd2 = __float2half2_rn(fx * fy);   // (y1,x1)

        int lx = min(max((int)x0f - bx_load, 0), 48);
        int ly = min(max((int)y0f - by_load, 0), 45);
        int idx = ly * LPITCH + lx;

        uint2 rA = sm[idx];                 // ds_read2_b64 {0,1}
        uint2 rC = sm[idx + 1];
        uint2 rB = sm[idx + LPITCH];        // ds_read2_b64 {49,50}
        uint2 rD = sm[idx + LPITCH + 1];

        __half2 a01 = *(const __half2*)&rA.x, a2 = *(const __half2*)&rA.y;
        __half2 c01 = *(const __half2*)&rC.x, c2 = *(const __half2*)&rC.y;
        __half2 b01 = *(const __half2*)&rB.x, b2 = *(const __half2*)&rB.y;
        __half2 d01 = *(const __half2*)&rD.x, d2 = *(const __half2*)&rD.y;

        __half2 r01 = __hmul2(wa2, a01);
        r01 = __hfma2(wb2, b01, r01);
        r01 = __hfma2(wc2, c01, r01);
        r01 = __hfma2(wd2, d01, r01);
        __half2 r2h = __hmul2(wa2, a2);
        r2h = __hfma2(wb2, b2, r2h);
        r2h = __hfma2(wc2, c2, r2h);
        r2h = __hfma2(wd2, d2, r2h);

        // Reference yields exactly 0 where clamped corners collapse.
        bool valid = (x >= 0.0f) && (x < 511.0f) && (y >= 0.0f) && (y < 511.0f);
        o[p * 3 + 0] = valid ? __low2float(r01)  : 0.0f;
        o[p * 3 + 1] = valid ? __high2float(r01) : 0.0f;
        o[p * 3 + 2] = valid ? __low2float(r2h)  : 0.0f;
    }

    // 4 px = 48 B contiguous, 16B-aligned (jb multiple of 4 -> 48B-aligned).
    float* po = out + (((size_t)b * OUT_H + (i0 + il)) * OUT_W + (j0 + jb)) * CHANS;
    ((float4*)po)[0] = make_float4(o[0], o[1], o[2],  o[3]);
    ((float4*)po)[1] = make_float4(o[4], o[5], o[6],  o[7]);
    ((float4*)po)[2] = make_float4(o[8], o[9], o[10], o[11]);
}

extern "C" void kernel_launch(void* const* d_in, const int* in_sizes, int n_in,
                              void* d_out, int out_size, void* d_ws, size_t ws_size,
                              hipStream_t stream) {
    const float* U     = (const float*)d_in[0];
    const float* theta = (const float*)d_in[1];
    float* out = (float*)d_out;

    int blocks = BATCH * (OUT_H / 32) * (OUT_W / 32);   // 16384
    st_bilinear_kernel<<<blocks, 256, 0, stream>>>(U, theta, out);
}

// Round 6
// 103.395 us; speedup vs baseline: 1.1346x; 1.1346x over previous
//
#include <hip/hip_runtime.h>
#include <hip/hip_fp16.h>

#define OUT_H 512
#define OUT_W 512
#define BATCH 64
#define CHANS 3

#define WROWS 48                  // staged rows
#define WPX   48                  // staged px per row
#define LPITCH 50                 // LDS row pitch in px slots (even: pair-aligned writes)
#define LSLOTS (WROWS * LPITCH)   // 2400 slots per array
#define IDX_MAX 2348              // clamp so idx+LPITCH+1 <= 2399 stays in-array

__global__ __launch_bounds__(256) void st_bilinear_kernel(
    const float* __restrict__ U,      // [B, H, W, C] f32
    const float* __restrict__ theta,  // [B, 1]
    float* __restrict__ out)          // [B, H, W, C] f32
{
    // SoA f16 staging: 4B granularity -> all 32 LDS banks reachable.
    __shared__ __align__(16) unsigned int smA[LSLOTS];  // half2 {c0,c1}
    __shared__ __align__(16) unsigned int smB[LSLOTS];  // half2 {c2, 0}

    // XCD-aware remap: give XCD k images [k*8, k*8+8) so each 3.1 MB image
    // stays resident in one XCD's 4 MB L2.
    int blk  = blockIdx.x;
    int lblk = (blk & 7) * 2048 + (blk >> 3);

    int b  = lblk >> 8;                 // image (uniform per block)
    int t  = lblk & 255;                // 16x16 tiles of 32x32 px
    int i0 = (t >> 4) << 5;
    int j0 = (t & 15) << 5;

    int tid = threadIdx.x;

    float tt = theta[b];
    float s, c;
    __sincosf(tt, &s, &c);

    // x = xb0 + c*jl - s*il ; y = yb0 + s*jl + c*il  ((2/511)*255.5 == 1)
    const float scale = 2.0f / 511.0f;
    float gx0 = (float)j0 * scale - 1.0f;
    float gy0 = (float)i0 * scale - 1.0f;
    float xb0 = (c * gx0 - s * gy0 + 1.0f) * 255.5f;
    float yb0 = (s * gx0 + c * gy0 + 1.0f) * 255.5f;

    // Source bbox of the 32x32 tile (linear map -> corner extremes).
    float xmin = xb0 + fminf(0.0f, 31.0f * c) + fminf(0.0f, -31.0f * s);
    float ymin = yb0 + fminf(0.0f, 31.0f * s) + fminf(0.0f,  31.0f * c);

    int bx0 = min(max((int)floorf(xmin), 0), OUT_W - 1);
    int by0 = min(max((int)floorf(ymin), 0), OUT_H - 1);
    int bx_load = min(bx0, OUT_W - WPX);    // 48x48 window always in-image
    int by_load = min(by0, OUT_H - WROWS);

    const float* Ub = U + (size_t)b * (OUT_H * OUT_W * CHANS);
    const float* gb = Ub + ((size_t)by_load * OUT_W + bx_load) * CHANS;

    // ---- staging: 1152 px-pairs (48x48), fully unrolled, loads hoisted ----
    // pair P -> row r = P/24, pair-in-row pr; px {2pr, 2pr+1} = 6 floats.
    float4 va[5];
    float2 vb[5];
#pragma unroll
    for (int it = 0; it < 5; ++it) {
        unsigned P = (unsigned)tid + 256u * it;
        if (it < 4 || tid < 128) {
            unsigned r  = P / 24u;
            unsigned pr = P - r * 24u;
            const float* p = gb + (size_t)r * (OUT_W * CHANS) + pr * 6u;
            va[it] = *(const float4*)p;       // 4B-aligned ok on gfx950
            vb[it] = *(const float2*)(p + 4);
        }
    }
#pragma unroll
    for (int it = 0; it < 5; ++it) {
        unsigned P = (unsigned)tid + 256u * it;
        if (it < 4 || tid < 128) {
            unsigned r  = P / 24u;
            unsigned pr = P - r * 24u;
            unsigned slot = r * LPITCH + pr * 2u;   // even -> 8B aligned
            float4 v = va[it]; float2 w = vb[it];
            __half2 ha0 = __floats2half2_rn(v.x, v.y);   // px0 {c0,c1}
            __half2 hb0 = __floats2half2_rn(v.z, 0.0f);  // px0 {c2,0}
            __half2 ha1 = __floats2half2_rn(v.w, w.x);   // px1 {c0,c1}
            __half2 hb1 = __floats2half2_rn(w.y, 0.0f);  // px1 {c2,0}
            uint2 wa, wb;
            wa.x = *(unsigned int*)&ha0; wa.y = *(unsigned int*)&ha1;
            wb.x = *(unsigned int*)&hb0; wb.y = *(unsigned int*)&hb1;
            *(uint2*)(smA + slot) = wa;   // ds_write_b64
            *(uint2*)(smB + slot) = wb;
        }
    }
    __syncthreads();

    // ---- compute: thread -> 4 consecutive px in one output row ----
    int il = tid >> 3;                  // 0..31
    int jb = (tid & 7) << 2;            // 0,4,...,28
    float ilf = (float)il;
    float xr = xb0 - s * ilf;           // x at (il, j0+0)
    float yr = yb0 + c * ilf;
    int Koff = by_load * LPITCH + bx_load;

    float o[12];
#pragma unroll
    for (int p = 0; p < 4; ++p) {
        float jlf = (float)(jb + p);
        float x = fmaf(c, jlf, xr);
        float y = fmaf(s, jlf, yr);

        int ix = __float2int_rd(x);     // v_cvt_flr_i32_f32
        int iy = __float2int_rd(y);
        float fx = x - (float)ix;
        float fy = y - (float)iy;

        int idx = iy * LPITCH + ix - Koff;      // = (iy-by)*50 + (ix-bx)
        idx = min(max(idx, 0), IDX_MAX);        // single clamp (v_med3)

        unsigned iA0 = smA[idx],          iA1 = smA[idx + 1];          // ds_read2
        unsigned iA2 = smA[idx + LPITCH], iA3 = smA[idx + LPITCH + 1]; // ds_read2
        unsigned iB0 = smB[idx],          iB1 = smB[idx + 1];
        unsigned iB2 = smB[idx + LPITCH], iB3 = smB[idx + LPITCH + 1];

        __half2 fx2 = __float2half2_rn(fx);
        __half2 fy2 = __float2half2_rn(fy);
        __half2 A0 = *(__half2*)&iA0, A1 = *(__half2*)&iA1;
        __half2 A2 = *(__half2*)&iA2, A3 = *(__half2*)&iA3;
        __half2 B0 = *(__half2*)&iB0, B1 = *(__half2*)&iB1;
        __half2 B2 = *(__half2*)&iB2, B3 = *(__half2*)&iB3;

        __half2 tA = __hfma2(fx2, __hsub2(A1, A0), A0);
        __half2 bA = __hfma2(fx2, __hsub2(A3, A2), A2);
        __half2 rA = __hfma2(fy2, __hsub2(bA, tA), tA);
        __half2 tB = __hfma2(fx2, __hsub2(B1, B0), B0);
        __half2 bB = __hfma2(fx2, __hsub2(B3, B2), B2);
        __half2 rB = __hfma2(fy2, __hsub2(bB, tB), tB);

        // Reference yields exactly 0 where clamped corners collapse
        // (x<0, x>=511, y<0, y>=511): weight pairs cancel.
        bool valid = (x >= 0.0f) && (x < 511.0f) && (y >= 0.0f) && (y < 511.0f);
        o[p * 3 + 0] = valid ? __low2float(rA)  : 0.0f;
        o[p * 3 + 1] = valid ? __high2float(rA) : 0.0f;
        o[p * 3 + 2] = valid ? __low2float(rB)  : 0.0f;
    }

    // 4 px = 48 B contiguous, 16B-aligned.
    float* po = out + (((size_t)b * OUT_H + (i0 + il)) * OUT_W + (j0 + jb)) * CHANS;
    ((float4*)po)[0] = make_float4(o[0], o[1], o[2],  o[3]);
    ((float4*)po)[1] = make_float4(o[4], o[5], o[6],  o[7]);
    ((float4*)po)[2] = make_float4(o[8], o[9], o[10], o[11]);
}

extern "C" void kernel_launch(void* const* d_in, const int* in_sizes, int n_in,
                              void* d_out, int out_size, void* d_ws, size_t ws_size,
                              hipStream_t stream) {
    const float* U     = (const float*)d_in[0];
    const float* theta = (const float*)d_in[1];
    float* out = (float*)d_out;

    int blocks = BATCH * (OUT_H / 32) * (OUT_W / 32);   // 16384
    st_bilinear_kernel<<<blocks, 256, 0, stream>>>(U, theta, out);
}